// Round 3
// baseline (46.037 us; speedup 1.0000x reference)
//
#include <hip/hip_runtime.h>

#define EMB 128
#define BM 128
#define THREADS 512

typedef __attribute__((ext_vector_type(8))) short bf16x8;   // 8 bf16 (4 VGPRs)
typedef __attribute__((ext_vector_type(4))) float f32x4;
typedef unsigned short u16;

__device__ __forceinline__ u16 f2bf(float f) {
    unsigned u = __builtin_bit_cast(unsigned, f);
    u += 0x7fffu + ((u >> 16) & 1u);           // round-to-nearest-even
    return (u16)(u >> 16);
}

// ---- merged pre-kernel ----
// blocks [0,500): Rp[j][n] = sum_k rel[j][k] * Dr[k][n]   (2 rows j per block)
// blocks [500,564): frag-major bf16 image of De:
//   Bimg[((kk*8+ni)*64 + lane)*8 + e] = bf16( De[kk*32+(lane>>4)*8+e][ni*16+(lane&15)] )
__global__ void setup_kernel(const float* __restrict__ rel,
                             const float* __restrict__ Dr,
                             const float* __restrict__ De,
                             float* __restrict__ Rp,
                             u16* __restrict__ Bimg, int nrel) {
    const int blk = blockIdx.x;
    if (blk < 500) {
        const int n = threadIdx.x & 127;
        const int j = blk * 2 + (threadIdx.x >> 7);
        if (j >= nrel) return;
        float a = 0.f;
        for (int k = 0; k < EMB; ++k)
            a = fmaf(rel[(size_t)j * EMB + k], Dr[(size_t)k * EMB + n], a);
        Rp[(size_t)j * EMB + n] = a;
    } else {
        const int idx  = (blk - 500) * 256 + threadIdx.x;   // 0..16383
        const int e    = idx & 7;
        const int lane = (idx >> 3) & 63;
        const int frag = idx >> 9;
        const int ni = frag & 7, kk = frag >> 3;
        const int k = kk * 32 + (lane >> 4) * 8 + e;
        const int n = ni * 16 + (lane & 15);
        Bimg[idx] = f2bf(De[(size_t)k * EMB + n]);
    }
}

// ---- main kernel ----
__global__ __launch_bounds__(THREADS, 4)
void projE_main(const int* __restrict__ triple,
                const float* __restrict__ ent,
                const float* __restrict__ bc,
                const float* __restrict__ Rp,
                const u16* __restrict__ Bimg,
                float* __restrict__ out)
{
    __shared__ u16 As[BM][EMB];     // 32KB, XOR-swizzled rows (h rows, bf16)
    __shared__ u16 Bs[16384];       // 32KB, frag-major De image (conflict-free)

    const int tid  = threadIdx.x;
    const int lane = tid & 63;
    const int w    = tid >> 6;      // wave 0..7, owns batch rows w*16..w*16+15
    const int l15  = lane & 15;
    const int l4   = lane >> 4;
    const int bm0  = blockIdx.x * BM;

    // ---- stage De image: 32KB linear copy, global -> LDS direct ----
    {
        const __attribute__((address_space(1))) char* gB =
            (const __attribute__((address_space(1))) char*)Bimg;
        __attribute__((address_space(3))) char* lB =
            (__attribute__((address_space(3))) char*)Bs;
        #pragma unroll
        for (int i = 0; i < 4; ++i) {
            const int off = (i * THREADS + tid) * 16;   // wave-uniform base + lane*16
            __builtin_amdgcn_global_load_lds(
                (const __attribute__((address_space(1))) void*)(gB + off),
                (__attribute__((address_space(3))) void*)(lB + off), 16, 0, 0);
        }
    }

    // ---- stage A: this wave's 16 h-rows -> bf16 LDS, swizzled ----
    {
        const int seg   = lane & 31;        // float4 segment within a 512B row
        const int rhalf = lane >> 5;
        #pragma unroll
        for (int it = 0; it < 8; ++it) {
            const int row  = w * 16 + it * 2 + rhalf;
            const int g    = bm0 + row;
            const int hidx = triple[g * 3];
            const float4 hv = *reinterpret_cast<const float4*>(ent + (size_t)hidx * EMB + seg * 4);
            ushort4 hp = { f2bf(hv.x), f2bf(hv.y), f2bf(hv.z), f2bf(hv.w) };
            *reinterpret_cast<ushort4*>(&As[row][(seg * 4) ^ ((row & 7) << 3)]) = hp;
        }
    }

    __syncthreads();   // the only barrier

    // ---- MFMA (swapped operands): C[de_n][batch] = De^T-frag (A) x h-frag (B) ----
    // C layout: col = l15 = batch row; row = 4*l4 + reg = de_n within fragment ci
    f32x4 acc[8];
    #pragma unroll
    for (int ci = 0; ci < 8; ++ci) acc[ci] = (f32x4){0.f, 0.f, 0.f, 0.f};

    const int arow = w * 16 + l15;
    const int asw  = (arow & 7) << 3;
    #pragma unroll
    for (int kk = 0; kk < 4; ++kk) {
        const bf16x8 h = *reinterpret_cast<const bf16x8*>(&As[arow][(kk * 32 + 8 * l4) ^ asw]);
        #pragma unroll
        for (int ci = 0; ci < 8; ++ci) {
            const bf16x8 d = *reinterpret_cast<const bf16x8*>(&Bs[(kk * 8 + ci) * 512 + lane * 8]);
            acc[ci] = __builtin_amdgcn_mfma_f32_16x16x32_bf16(d, h, acc[ci], 0, 0, 0);
        }
    }

    // ---- epilogue (no barrier, all float4): f = tanh(acc + Rp[ridx] + bc); out = sigmoid(f . t) ----
    const int g    = bm0 + w * 16 + l15;       // this lane's batch row
    const int ridx = triple[g * 3 + 1];
    const int tidx = triple[g * 3 + 2];
    const float* rp = Rp  + (size_t)ridx * EMB;
    const float* bp = bc  + (size_t)g    * EMB;
    const float* tp = ent + (size_t)tidx * EMB;

    float dot = 0.f;
    #pragma unroll
    for (int ci = 0; ci < 8; ++ci) {
        const int col = ci * 16 + 4 * l4;      // 4 consecutive cols per lane
        const float4 r4 = *reinterpret_cast<const float4*>(rp + col);
        const float4 b4 = *reinterpret_cast<const float4*>(bp + col);
        const float4 t4 = *reinterpret_cast<const float4*>(tp + col);
        #pragma unroll
        for (int e = 0; e < 4; ++e) {
            const float x  = acc[ci][e] + (&r4.x)[e] + (&b4.x)[e];
            const float e2 = __expf(2.f * x);
            const float fv = 1.f - __fdividef(2.f, e2 + 1.f);   // tanh(x), inf-safe
            dot = fmaf(fv, (&t4.x)[e], dot);
        }
    }
    dot += __shfl_xor(dot, 16);
    dot += __shfl_xor(dot, 32);
    if (lane < 16) out[g] = __fdividef(1.f, 1.f + __expf(-dot));
}

extern "C" void kernel_launch(void* const* d_in, const int* in_sizes, int n_in,
                              void* d_out, int out_size, void* d_ws, size_t ws_size,
                              hipStream_t stream) {
    const int*   triple = (const int*)  d_in[0];
    const float* ent    = (const float*)d_in[1];
    const float* rel    = (const float*)d_in[2];
    const float* De     = (const float*)d_in[3];
    const float* Dr     = (const float*)d_in[4];
    const float* bc     = (const float*)d_in[5];
    float* out = (float*)d_out;

    const int batch = in_sizes[0] / 3;          // 131072
    const int nrel  = in_sizes[2] / EMB;        // 1000

    float* Rp = (float*)d_ws;                           // 512000 B
    u16* Bimg = (u16*)((char*)d_ws + 524288);           // 32 KB

    setup_kernel<<<dim3(564), dim3(256), 0, stream>>>(rel, Dr, De, Rp, Bimg, nrel);
    projE_main<<<dim3(batch / BM), dim3(THREADS), 0, stream>>>(triple, ent, bc, Rp, Bimg, out);
}